// Round 4
// baseline (559.329 us; speedup 1.0000x reference)
//
#include <hip/hip_runtime.h>

#define BATCH 8192
#define SEQ 512
#define INND 5
#define HID 64
#define STRIDE 104  // shorts per LDS row (96 used + pad); 208B = multiple of 16

typedef __attribute__((ext_vector_type(8))) short short8;
typedef __attribute__((ext_vector_type(4))) float f32x4;
typedef __attribute__((ext_vector_type(2))) float f32x2;

__device__ __forceinline__ unsigned short f2bf(float f) {
  union { float f; unsigned u; } v; v.f = f;
  unsigned r = v.u + 0x7FFFu + ((v.u >> 16) & 1u);
  return (unsigned short)(r >> 16);
}
__device__ __forceinline__ float bf2f(unsigned short s) {
  union { unsigned u; float f; } v; v.u = ((unsigned)s) << 16;
  return v.f;
}
#define RCP(x) __builtin_amdgcn_rcpf(x)

// One WG (4 waves) owns 16 batch rows. MFMA operand-swapped: D = W_cat · H^T,
// so thread (w,kg,q,l15) owns gates[gatecol=64X+16w+4kg+q][batch=l15] -> its 4
// h outputs are CONTIGUOUS in hidden dim (one b64 LDS write).
// W rows pre-scaled: i,f,o by -1, g by -2, so acc == exp() argument directly.
// K-extension: k 0..63 = h, 64..68 = x_t, 69 = 1.0 (bias), rest 0.
// hbuf columns XOR-swizzled: key=(row&7)<<3 for k<64, (row&3)<<3 for k>=64.
// NOTE: swizzled offsets are ALWAYS computed before adding the row base —
// XOR on the full address (round 2/3's rd1 = rd0^32) corrupts rows whose
// base has bit 5 set.
__global__ __launch_bounds__(256) void lstm_kernel(
    const float* __restrict__ inputs, const float* __restrict__ W_ih,
    const float* __restrict__ W_hh, const float* __restrict__ b_ih,
    const float* __restrict__ b_hh, const float* __restrict__ fc_w,
    const float* __restrict__ fc_b, float* __restrict__ out) {
  __shared__ unsigned short hbuf[2][16][STRIDE] __attribute__((aligned(16)));

  const int tid = threadIdx.x;
  const int lane = tid & 63;
  const int w = tid >> 6;    // wave 0..3
  const int l15 = lane & 15; // batch row (local)
  const int kg = lane >> 4;  // k-group / D row-group
  const int l7 = l15 & 7;
  const int b0 = blockIdx.x * 16;

  // ---------------- W_cat fragments (registers), pre-scaled ----------------
  // A-operand frag for tile X, kstep s: lane holds Wcat[gatecol=64X+16w+l15][k],
  // k = 32s + 8kg + j
  short8 wf[4][3];
#pragma unroll
  for (int X = 0; X < 4; ++X) {
    const float sc = (X == 2) ? -2.f : -1.f;
    const int col = 64 * X + 16 * w + l15;
    const float* wr = W_hh + col * 64;
#pragma unroll
    for (int s = 0; s < 2; ++s) {
      const float* p = wr + 32 * s + 8 * kg;
      short8 v;
#pragma unroll
      for (int j = 0; j < 8; ++j) v[j] = (short)f2bf(sc * p[j]);
      wf[X][s] = v;
    }
    short8 e;
#pragma unroll
    for (int j = 0; j < 8; ++j) e[j] = 0;
    if (kg == 0) {  // k = 64..71
#pragma unroll
      for (int j = 0; j < 5; ++j) e[j] = (short)f2bf(sc * W_ih[col * 5 + j]);
      e[5] = (short)f2bf(sc * (b_ih[col] + b_hh[col]));  // pairs with const 1.0
    }
    wf[X][2] = e;
  }

  // ---------------- per-thread LDS indices (constant over t) ---------------
  unsigned short* const hb0 = &hbuf[0][0][0];
  const int rd0 = l15 * STRIDE + ((kg ^ l7) << 3);              // logical k 8kg
  const int rd1 = l15 * STRIDE + (((4 | kg) ^ l7) << 3);        // logical k 32+8kg
  const int rd2 = l15 * STRIDE + 64 + ((kg ^ (l15 & 3)) << 3);  // k 64+8kg
  const int hwr = l15 * STRIDE + (((w << 4) | (kg << 2)) ^ (l7 << 3));

  // ---------------- x writer lanes ----------------
  const bool writer = (tid < 16 * INND);  // 80 lanes: (row,i)
  const int wrow = tid / INND;
  const int wi = tid - wrow * INND;
  const float* xptr = inputs + (size_t)(b0 + wrow) * (SEQ * INND) + wi;
  const int xcol = 64 + (wi | ((wrow & 3) << 3));  // swizzled x slot

  // ---------------- LDS init ----------------
  for (int i = tid; i < 2 * 16 * STRIDE; i += 256) hb0[i] = 0;
  __syncthreads();
  if (tid < 32) {  // constant-1 column (logical 69), both buffers
    const int r = tid & 15;
    hbuf[tid >> 4][r][64 + (5 | ((r & 3) << 3))] = 0x3F80;
  }
  float x_next = 0.f;
  if (writer) {
    hbuf[0][wrow][xcol] = f2bf(xptr[0]);
    x_next = xptr[INND];
  }
  __syncthreads();

  // ---------------- recurrence ----------------
  f32x2 cst[2] = {{0.f, 0.f}, {0.f, 0.f}};  // c for hid 16w+4kg+{0..3}, batch l15
  for (int t = 0; t < SEQ; ++t) {
    const int cur = t & 1, nxt = cur ^ 1;

    float x_n2 = 0.f;
    if (writer && t + 2 < SEQ) x_n2 = xptr[(t + 2) * INND];

    const unsigned short* hc = hb0 + cur * (16 * STRIDE);
    f32x4 acc0 = {0.f, 0.f, 0.f, 0.f};
    f32x4 acc1 = {0.f, 0.f, 0.f, 0.f};
    f32x4 acc2 = {0.f, 0.f, 0.f, 0.f};
    f32x4 acc3 = {0.f, 0.f, 0.f, 0.f};
    {
      const short8 a0 = *(const short8*)(hc + rd0);
      acc0 = __builtin_amdgcn_mfma_f32_16x16x32_bf16(wf[0][0], a0, acc0, 0, 0, 0);
      acc1 = __builtin_amdgcn_mfma_f32_16x16x32_bf16(wf[1][0], a0, acc1, 0, 0, 0);
      acc2 = __builtin_amdgcn_mfma_f32_16x16x32_bf16(wf[2][0], a0, acc2, 0, 0, 0);
      acc3 = __builtin_amdgcn_mfma_f32_16x16x32_bf16(wf[3][0], a0, acc3, 0, 0, 0);
      const short8 a1 = *(const short8*)(hc + rd1);
      acc0 = __builtin_amdgcn_mfma_f32_16x16x32_bf16(wf[0][1], a1, acc0, 0, 0, 0);
      acc1 = __builtin_amdgcn_mfma_f32_16x16x32_bf16(wf[1][1], a1, acc1, 0, 0, 0);
      acc2 = __builtin_amdgcn_mfma_f32_16x16x32_bf16(wf[2][1], a1, acc2, 0, 0, 0);
      acc3 = __builtin_amdgcn_mfma_f32_16x16x32_bf16(wf[3][1], a1, acc3, 0, 0, 0);
      const short8 a2 = *(const short8*)(hc + rd2);
      acc0 = __builtin_amdgcn_mfma_f32_16x16x32_bf16(wf[0][2], a2, acc0, 0, 0, 0);
      acc1 = __builtin_amdgcn_mfma_f32_16x16x32_bf16(wf[1][2], a2, acc1, 0, 0, 0);
      acc2 = __builtin_amdgcn_mfma_f32_16x16x32_bf16(wf[2][2], a2, acc2, 0, 0, 0);
      acc3 = __builtin_amdgcn_mfma_f32_16x16x32_bf16(wf[3][2], a2, acc3, 0, 0, 0);
    }

    // gates -> c,h ; acc holds t_i=-z_i, t_f=-z_f, t_g=-2z_g, t_o=-z_o
    unsigned pk[2];
#pragma unroll
    for (int p = 0; p < 2; ++p) {
      f32x2 ti = {acc0[2 * p], acc0[2 * p + 1]};
      f32x2 tf = {acc1[2 * p], acc1[2 * p + 1]};
      f32x2 tg = {acc2[2 * p], acc2[2 * p + 1]};
      f32x2 to = {acc3[2 * p], acc3[2 * p + 1]};
      ti.x = fminf(ti.x, 17.f); ti.y = fminf(ti.y, 17.f);
      tf.x = fminf(tf.x, 17.f); tf.y = fminf(tf.y, 17.f);
      tg.x = fminf(tg.x, 34.f); tg.y = fminf(tg.y, 34.f);
      to.x = fminf(to.x, 17.f); to.y = fminf(to.y, 17.f);
      f32x2 Ei, Ef, Eg, Eo;
      Ei.x = __expf(ti.x); Ei.y = __expf(ti.y);
      Ef.x = __expf(tf.x); Ef.y = __expf(tf.y);
      Eg.x = __expf(tg.x); Eg.y = __expf(tg.y);
      Eo.x = __expf(to.x); Eo.y = __expf(to.y);
      const f32x2 ai = Ei + 1.f, af = Ef + 1.f, ag = Eg + 1.f, ao = Eo + 1.f;
      const f32x2 u = ai * ag, v = af * ao;
      const f32x2 P = u * v;
      f32x2 r; r.x = RCP(P.x); r.y = RCP(P.y);
      const f32x2 rv = r * v;  // 1/(ai*ag)
      const f32x2 ru = r * u;  // 1/(af*ao)
      const f32x2 Pig = (1.f - Eg) * rv;  // sigmoid(zi)*tanh(zg)
      const f32x2 sf = ru * ao;           // sigmoid(zf)
      const f32x2 so = ru * af;           // sigmoid(zo)
      const f32x2 c = sf * cst[p] + Pig;
      cst[p] = c;
      f32x2 tc;
      tc.x = fminf(-2.f * c.x, 80.f); tc.y = fminf(-2.f * c.y, 80.f);
      f32x2 Ec; Ec.x = __expf(tc.x); Ec.y = __expf(tc.y);
      const f32x2 ac = Ec + 1.f;
      f32x2 rc; rc.x = RCP(ac.x); rc.y = RCP(ac.y);
      const f32x2 th = (1.f - Ec) * rc;   // tanh(c)
      const f32x2 h = so * th;
      pk[p] = ((unsigned)f2bf(h.x)) | (((unsigned)f2bf(h.y)) << 16);
    }
    {
      uint2 pkv; pkv.x = pk[0]; pkv.y = pk[1];
      *(uint2*)(hb0 + nxt * (16 * STRIDE) + hwr) = pkv;  // 4 bf16 h, one b64
    }
    if (writer && t + 1 < SEQ) hbuf[nxt][wrow][xcol] = f2bf(x_next);
    x_next = x_n2;
    __syncthreads();
  }

  // ---------------- epilogue: out = leaky_relu(h @ fc_w^T + fc_b) ----------
  // final h (t=SEQ) is in hbuf[0] (SEQ even)
  if (tid < 64) {
    const int row = tid >> 2, seg = tid & 3;
    const int key = (row & 7) << 3;
    float sum = 0.f;
#pragma unroll
    for (int j = 0; j < 16; ++j)
      sum += bf2f(hbuf[0][row][(seg * 16 + j) ^ key]) * fc_w[seg * 16 + j];
    sum += __shfl_xor(sum, 1);
    sum += __shfl_xor(sum, 2);
    if (seg == 0) {
      const float p = sum + fc_b[0];
      out[b0 + row] = p > 0.f ? p : 0.01f * p;
    }
  }
}

extern "C" void kernel_launch(void* const* d_in, const int* in_sizes, int n_in,
                              void* d_out, int out_size, void* d_ws, size_t ws_size,
                              hipStream_t stream) {
  const float* inputs = (const float*)d_in[0];
  const float* W_ih = (const float*)d_in[1];
  const float* W_hh = (const float*)d_in[2];
  const float* b_ih = (const float*)d_in[3];
  const float* b_hh = (const float*)d_in[4];
  const float* fc_w = (const float*)d_in[5];
  const float* fc_b = (const float*)d_in[6];
  float* out = (float*)d_out;

  lstm_kernel<<<BATCH / 16, 256, 0, stream>>>(inputs, W_ih, W_hh, b_ih, b_hh,
                                              fc_w, fc_b, out);
}

// Round 5
// 470.007 us; speedup vs baseline: 1.1900x; 1.1900x over previous
//
#include <hip/hip_runtime.h>

#define BATCH 8192
#define SEQ 512
#define INND 5
#define HID 64
#define STRIDE 104  // shorts per LDS row; 52 dwords = 4*(5 mod 8): odd-multiplier
                    // rotation -> row-major reads are bank-uniform WITHOUT swizzle.

typedef __attribute__((ext_vector_type(8))) short short8;
typedef __attribute__((ext_vector_type(4))) float f32x4;
typedef __attribute__((ext_vector_type(2))) float f32x2;

__device__ __forceinline__ unsigned short f2bf(float f) {
  union { float f; unsigned u; } v; v.f = f;
  unsigned r = v.u + 0x7FFFu + ((v.u >> 16) & 1u);
  return (unsigned short)(r >> 16);
}
__device__ __forceinline__ float bf2f(unsigned short s) {
  union { unsigned u; float f; } v; v.u = ((unsigned)s) << 16;
  return v.f;
}
#define RCP(x) __builtin_amdgcn_rcpf(x)
#define EXP2(x) __builtin_amdgcn_exp2f(x)
#define NL2E 1.44269504088896340736f  // log2(e)

// One WG (4 waves) owns 16 batch rows. Operand-swapped MFMA: D = W_cat · H^T;
// thread (w,kg,q,l15) owns gate[64X+16w+4kg+q][batch=l15] -> 4 consecutive
// hidden h outputs -> one b64 LDS write at column 16w+4kg (no swizzle).
// W rows pre-scaled by -log2e (g: -2log2e): MFMA acc IS the v_exp_f32 arg.
// K-extension: k 0..63 = h, 64..68 = x_t, 69 = 1.0 (bias), rest 0.
__global__ __launch_bounds__(256) void lstm_kernel(
    const float* __restrict__ inputs, const float* __restrict__ W_ih,
    const float* __restrict__ W_hh, const float* __restrict__ b_ih,
    const float* __restrict__ b_hh, const float* __restrict__ fc_w,
    const float* __restrict__ fc_b, float* __restrict__ out) {
  __shared__ unsigned short hbuf[2][16][STRIDE] __attribute__((aligned(16)));

  const int tid = threadIdx.x;
  const int lane = tid & 63;
  const int w = tid >> 6;    // wave 0..3
  const int l15 = lane & 15; // batch row (local)
  const int kg = lane >> 4;  // k-group / D row-group
  const int b0 = blockIdx.x * 16;

  // ---------------- W_cat fragments (registers), exp2-pre-scaled -----------
  short8 wf[4][3];
#pragma unroll
  for (int X = 0; X < 4; ++X) {
    const float sc = (X == 2) ? (-2.f * NL2E) : (-NL2E);
    const int col = 64 * X + 16 * w + l15;
    const float* wr = W_hh + col * 64;
#pragma unroll
    for (int s = 0; s < 2; ++s) {
      const float* p = wr + 32 * s + 8 * kg;
      short8 v;
#pragma unroll
      for (int j = 0; j < 8; ++j) v[j] = (short)f2bf(sc * p[j]);
      wf[X][s] = v;
    }
    short8 e;
#pragma unroll
    for (int j = 0; j < 8; ++j) e[j] = 0;
    if (kg == 0) {  // k = 64..71
#pragma unroll
      for (int j = 0; j < 5; ++j) e[j] = (short)f2bf(sc * W_ih[col * 5 + j]);
      e[5] = (short)f2bf(sc * (b_ih[col] + b_hh[col]));  // pairs with const 1.0
    }
    wf[X][2] = e;
  }

  // ------------- per-thread LDS indices (round-1 proven pattern) -----------
  unsigned short* const hb0 = &hbuf[0][0][0];
  const int rd0 = l15 * STRIDE + 8 * kg;  // k = 8kg..8kg+7
  const int rd1 = rd0 + 32;               // k = 32+8kg
  const int rd2 = rd0 + 64;               // k = 64+8kg
  const int hwr = l15 * STRIDE + 16 * w + 4 * kg;  // 4 consecutive h (b64)

  // ---------------- x writer lanes ----------------
  const bool writer = (tid < 16 * INND);  // 80 lanes: (row,i)
  const int wrow = tid / INND;
  const int wi = tid - wrow * INND;
  const float* xptr = inputs + (size_t)(b0 + wrow) * (SEQ * INND) + wi;
  const int xcol = 64 + wi;

  // ---------------- LDS init ----------------
  for (int i = tid; i < 2 * 16 * STRIDE; i += 256) hb0[i] = 0;
  __syncthreads();
  if (tid < 32) hbuf[tid >> 4][tid & 15][69] = 0x3F80;  // constant-1 column
  float x_next = 0.f;
  if (writer) {
    hbuf[0][wrow][xcol] = f2bf(xptr[0]);
    x_next = xptr[INND];
  }
  __syncthreads();

  // ---------------- recurrence ----------------
  f32x2 cst[2] = {{0.f, 0.f}, {0.f, 0.f}};
  for (int t = 0; t < SEQ; ++t) {
    const int nxt = (t & 1) ^ 1;

    float x_n2 = 0.f;
    if (writer && t + 2 < SEQ) x_n2 = xptr[(t + 2) * INND];

    const unsigned short* hc = hb0 + (t & 1) * (16 * STRIDE);
    f32x4 acc0 = {0.f, 0.f, 0.f, 0.f};
    f32x4 acc1 = {0.f, 0.f, 0.f, 0.f};
    f32x4 acc2 = {0.f, 0.f, 0.f, 0.f};
    f32x4 acc3 = {0.f, 0.f, 0.f, 0.f};
    {
      const short8 a0 = *(const short8*)(hc + rd0);
      acc0 = __builtin_amdgcn_mfma_f32_16x16x32_bf16(wf[0][0], a0, acc0, 0, 0, 0);
      acc1 = __builtin_amdgcn_mfma_f32_16x16x32_bf16(wf[1][0], a0, acc1, 0, 0, 0);
      acc2 = __builtin_amdgcn_mfma_f32_16x16x32_bf16(wf[2][0], a0, acc2, 0, 0, 0);
      acc3 = __builtin_amdgcn_mfma_f32_16x16x32_bf16(wf[3][0], a0, acc3, 0, 0, 0);
      const short8 a1 = *(const short8*)(hc + rd1);
      acc0 = __builtin_amdgcn_mfma_f32_16x16x32_bf16(wf[0][1], a1, acc0, 0, 0, 0);
      acc1 = __builtin_amdgcn_mfma_f32_16x16x32_bf16(wf[1][1], a1, acc1, 0, 0, 0);
      acc2 = __builtin_amdgcn_mfma_f32_16x16x32_bf16(wf[2][1], a1, acc2, 0, 0, 0);
      acc3 = __builtin_amdgcn_mfma_f32_16x16x32_bf16(wf[3][1], a1, acc3, 0, 0, 0);
      const short8 a2 = *(const short8*)(hc + rd2);
      acc0 = __builtin_amdgcn_mfma_f32_16x16x32_bf16(wf[0][2], a2, acc0, 0, 0, 0);
      acc1 = __builtin_amdgcn_mfma_f32_16x16x32_bf16(wf[1][2], a2, acc1, 0, 0, 0);
      acc2 = __builtin_amdgcn_mfma_f32_16x16x32_bf16(wf[2][2], a2, acc2, 0, 0, 0);
      acc3 = __builtin_amdgcn_mfma_f32_16x16x32_bf16(wf[3][2], a2, acc3, 0, 0, 0);
    }

    // acc holds exp2-args: -zi*l2e, -zf*l2e, -2zg*l2e, -zo*l2e
    unsigned pk[2];
#pragma unroll
    for (int p = 0; p < 2; ++p) {
      f32x2 Ei, Ef, Eg, Eo;
      Ei.x = EXP2(acc0[2 * p]); Ei.y = EXP2(acc0[2 * p + 1]);
      Ef.x = EXP2(acc1[2 * p]); Ef.y = EXP2(acc1[2 * p + 1]);
      Eg.x = EXP2(acc2[2 * p]); Eg.y = EXP2(acc2[2 * p + 1]);
      Eo.x = EXP2(acc3[2 * p]); Eo.y = EXP2(acc3[2 * p + 1]);
      const f32x2 ai = Ei + 1.f, af = Ef + 1.f, ag = Eg + 1.f, ao = Eo + 1.f;
      const f32x2 u = ai * ag, vv = af * ao;
      const f32x2 P = u * vv;
      f32x2 r; r.x = RCP(P.x); r.y = RCP(P.y);
      const f32x2 rv = r * vv;   // 1/(ai*ag)
      const f32x2 ru = r * u;    // 1/(af*ao)
      const f32x2 si = rv * ag;  // sigmoid(zi)
      const f32x2 sg2 = rv * ai; // sigmoid(2 zg)
      const f32x2 sf = ru * ao;  // sigmoid(zf)
      const f32x2 so = ru * af;  // sigmoid(zo)
      const f32x2 tg = 2.f * sg2 - 1.f;  // tanh(zg)
      const f32x2 c = sf * cst[p] + si * tg;
      cst[p] = c;
      f32x2 tc = c * (-2.f * NL2E);
      tc.x = fminf(tc.x, 49.f); tc.y = fminf(tc.y, 49.f);
      f32x2 Ec; Ec.x = EXP2(tc.x); Ec.y = EXP2(tc.y);
      const f32x2 ac = Ec + 1.f;
      f32x2 rc; rc.x = RCP(ac.x); rc.y = RCP(ac.y);
      const f32x2 th = 2.f * rc - 1.f;  // tanh(c)
      const f32x2 h = so * th;
      asm("v_cvt_pk_bf16_f32 %0, %1, %2" : "=v"(pk[p]) : "v"(h.x), "v"(h.y));
    }
    {
      uint2 pkv; pkv.x = pk[0]; pkv.y = pk[1];
      *(uint2*)(hb0 + nxt * (16 * STRIDE) + hwr) = pkv;  // 4 bf16 h, one b64
    }
    if (writer && t + 1 < SEQ) hbuf[nxt][wrow][xcol] = f2bf(x_next);
    x_next = x_n2;
    __syncthreads();
  }

  // ---------------- epilogue: out = leaky_relu(h @ fc_w^T + fc_b) ----------
  if (tid < 64) {
    const int row = tid >> 2, seg = tid & 3;
    float sum = 0.f;
#pragma unroll
    for (int j = 0; j < 16; ++j)
      sum += bf2f(hbuf[0][row][seg * 16 + j]) * fc_w[seg * 16 + j];
    sum += __shfl_xor(sum, 1);
    sum += __shfl_xor(sum, 2);
    if (seg == 0) {
      const float p = sum + fc_b[0];
      out[b0 + row] = p > 0.f ? p : 0.01f * p;
    }
  }
}

extern "C" void kernel_launch(void* const* d_in, const int* in_sizes, int n_in,
                              void* d_out, int out_size, void* d_ws, size_t ws_size,
                              hipStream_t stream) {
  const float* inputs = (const float*)d_in[0];
  const float* W_ih = (const float*)d_in[1];
  const float* W_hh = (const float*)d_in[2];
  const float* b_ih = (const float*)d_in[3];
  const float* b_hh = (const float*)d_in[4];
  const float* fc_w = (const float*)d_in[5];
  const float* fc_b = (const float*)d_in[6];
  float* out = (float*)d_out;

  lstm_kernel<<<BATCH / 16, 256, 0, stream>>>(inputs, W_ih, W_hh, b_ih, b_hh,
                                              fc_w, fc_b, out);
}